// Round 10
// baseline (5176.213 us; speedup 1.0000x reference)
//
#include <hip/hip_runtime.h>
#include <stdint.h>

#define BATCH  1024
#define SEQLEN 15
#define NGATE  2048
#define NVOCAB 11998
#define FEATS  4096

typedef __attribute__((ext_vector_type(8)))  short  s8v;     // 8 bf16 bit patterns
typedef __attribute__((ext_vector_type(16))) float  f32x16;  // 32x32 MFMA acc
typedef __attribute__((ext_vector_type(8)))  unsigned short us8;

__device__ __forceinline__ unsigned short f2bf(float f) {
    unsigned u = __float_as_uint(f);
    u += 0x7FFFu + ((u >> 16) & 1u);
    return (unsigned short)(u >> 16);
}
__device__ __forceinline__ float bf2f(unsigned short h) {
    return __uint_as_float(((unsigned)h) << 16);
}
struct bfpair { unsigned short hi, lo; };
__device__ __forceinline__ bfpair split2v(float v) {
    bfpair r;
    r.hi = f2bf(v);
    r.lo = f2bf(v - bf2f(r.hi));
    return r;
}
__device__ __forceinline__ void split8(const float* __restrict__ s, us8& vh, us8& vl) {
    #pragma unroll
    for (int e = 0; e < 8; ++e) {
        bfpair q = split2v(s[e]);
        vh[e] = q.hi; vl[e] = q.lo;
    }
}

// async 16B-per-lane global->LDS; LDS dest = wave-uniform base + lane*16
__device__ __forceinline__ void async_cp16(const void* g, void* l) {
    __builtin_amdgcn_global_load_lds(
        (const __attribute__((address_space(1))) unsigned int*)g,
        (__attribute__((address_space(3))) unsigned int*)l, 16, 0, 0);
}

// ---------------------------------------------------------------------------
// prep: Wcat blocked [128 kc][2048 row][8] = split([W_ih | W_hh]); bsum
// ---------------------------------------------------------------------------
__global__ void prep_wcat_blk(const float* __restrict__ W_ih, const float* __restrict__ W_hh,
                              const float* __restrict__ b_ih, const float* __restrict__ b_hh,
                              unsigned short* __restrict__ hi, unsigned short* __restrict__ lo,
                              float* __restrict__ bsum) {
    int idx = blockIdx.x * 256 + threadIdx.x;   // 128*2048
    int kc = idx >> 11, row = idx & 2047;
    int k = kc << 3;
    const float* src = (k < 512) ? (W_ih + (size_t)row * 512 + k)
                                 : (W_hh + (size_t)row * 512 + (k - 512));
    us8 vh, vl; split8(src, vh, vl);
    *(us8*)(hi + (size_t)idx * 8) = vh;
    *(us8*)(lo + (size_t)idx * 8) = vl;
    if (idx < NGATE) bsum[idx] = b_ih[idx] + b_hh[idx];
}

// src [R][K] fp32 -> hi/lo [K/8][R][8] bf16. grid: (ceil(R/256), K/8)
__global__ void prep_blk(const float* __restrict__ src,
                         unsigned short* __restrict__ hi, unsigned short* __restrict__ lo,
                         int R, int K) {
    int row = blockIdx.x * 256 + threadIdx.x;
    if (row >= R) return;
    int kc = blockIdx.y;
    us8 vh, vl; split8(src + (size_t)row * K + (kc << 3), vh, vl);
    size_t o = ((size_t)kc * R + row) * 8;
    *(us8*)(hi + o) = vh;
    *(us8*)(lo + o) = vl;
}

// ---------------------------------------------------------------------------
// v12 GEMM body: PRODUCER-CONSUMER wave specialization. 512 threads = 8 waves:
//   waves 4-7 (producers): stage 32 KB tiles (A+B, hi+lo, 4 kc) into a
//     3-buffer LDS ring via global_load_lds, 8 cp16/wave/tile. Per-wave
//     COUNTED s_waitcnt vmcnt(8): certifies tile t+1 complete while t+2
//     stays in flight. Raw s_barrier (counts matched with consumers).
//   waves 0-3 (consumers): pure ds_read + MFMA, __syncthreads() only (their
//     implicit vmcnt(0) is free: they issue NO vmem in the loop). Never
//     stall on global memory -> MFMA pipe stays fed.
// Ring: step t reads buf[t%3], producer writes buf[(t+2)%3] (consumed at
// t-1, barrier-protected). Prologue barrier + 16 loop barriers, both roles.
// Producers exit before epilogue (no barriers after loop in either role).
// MFMA per-accumulator FP chain = R0's original (per st: hh x4, hl x4,
// lh x4) and A/B bytes identical -> bit-identical tokens.
// MODE 0: store C. MODE 1: fused bias + packed argmax.
// ---------------------------------------------------------------------------
template<int MODE>
__device__ __forceinline__ void gemm_pc(
    const unsigned short* __restrict__ Ahi, const unsigned short* __restrict__ Alo, int aRows,
    const unsigned short* __restrict__ Bhi, const unsigned short* __restrict__ Blo, int bRows,
    float* __restrict__ C, int ldc,
    size_t akstride, size_t bkstride, size_t czstride,
    int bm, int bn, int kz,
    const float* __restrict__ bias, unsigned long long* __restrict__ packed)
{
    __shared__ short s3[3][4][4][128][8];   // tile, {Ahi,Alo,Bhi,Blo}, kc_l, row, 8 = 96 KB

    Ahi += (size_t)kz * akstride;  Alo += (size_t)kz * akstride;
    Bhi += (size_t)kz * bkstride;  Blo += (size_t)kz * bkstride;
    if (MODE == 0) C += (size_t)kz * czstride;

    const int tid  = threadIdx.x;
    const int lane = tid & 63, wave = tid >> 6;   // 0..7

    if (wave >= 4) {
        // ---------------- producer ----------------
        const int wp = wave - 4;
        auto stage = [&](int t) {
            const int kc0  = t << 2;
            const int bufi = t % 3;
            #pragma unroll
            for (int p = 0; p < 8; ++p) {
                int s = p * 4 + wp;               // 0..31, wave-uniform
                int arr = s >> 3, rem = s & 7;
                int kc_l = rem >> 1, rh = rem & 1;
                int row = rh * 64 + lane;
                const unsigned short* src;
                if (arr < 2) {
                    size_t go = ((size_t)(kc0 + kc_l) * aRows + (bm + row)) * 8;
                    src = (arr == 0 ? Ahi : Alo) + go;
                } else {
                    int brow = bn + row; if (brow > bRows - 1) brow = bRows - 1;
                    size_t go = ((size_t)(kc0 + kc_l) * bRows + brow) * 8;
                    src = (arr == 2 ? Bhi : Blo) + go;
                }
                async_cp16(src, &s3[bufi][arr][kc_l][rh * 64][0]);
            }
        };
        stage(0);
        stage(1);
        asm volatile("s_waitcnt vmcnt(8)" ::: "memory");   // tile 0 complete
        __builtin_amdgcn_s_barrier();
        for (int t = 0; t < 16; ++t) {
            if (t + 2 < 16) {
                stage(t + 2);
                asm volatile("s_waitcnt vmcnt(8)" ::: "memory");  // t+1 complete, t+2 flying
            } else {
                asm volatile("s_waitcnt vmcnt(0)" ::: "memory");  // drain tail
            }
            __builtin_amdgcn_s_barrier();
        }
        return;   // no epilogue, no further barriers
    }

    // ---------------- consumer ----------------
    const int wm = wave & 1, wn = wave >> 1;
    const int col = lane & 31, kh = lane >> 5;

    f32x16 acc[2][2] = {};

    __syncthreads();   // matches producer prologue barrier (vmcnt(0) free here)

    for (int t = 0; t < 16; ++t) {
        const int bufi = t % 3;
        #pragma unroll
        for (int st = 0; st < 2; ++st) {
            const int kl = 2 * st + kh;
            s8v ah0 = *(const s8v*)&s3[bufi][0][kl][wm * 64 +      col][0];
            s8v ah1 = *(const s8v*)&s3[bufi][0][kl][wm * 64 + 32 + col][0];
            s8v al0 = *(const s8v*)&s3[bufi][1][kl][wm * 64 +      col][0];
            s8v al1 = *(const s8v*)&s3[bufi][1][kl][wm * 64 + 32 + col][0];
            s8v bh0 = *(const s8v*)&s3[bufi][2][kl][wn * 64 +      col][0];
            s8v bh1 = *(const s8v*)&s3[bufi][2][kl][wn * 64 + 32 + col][0];
            s8v bl0 = *(const s8v*)&s3[bufi][3][kl][wn * 64 +      col][0];
            s8v bl1 = *(const s8v*)&s3[bufi][3][kl][wn * 64 + 32 + col][0];
            acc[0][0] = __builtin_amdgcn_mfma_f32_32x32x16_bf16(ah0, bh0, acc[0][0], 0, 0, 0);
            acc[0][1] = __builtin_amdgcn_mfma_f32_32x32x16_bf16(ah0, bh1, acc[0][1], 0, 0, 0);
            acc[1][0] = __builtin_amdgcn_mfma_f32_32x32x16_bf16(ah1, bh0, acc[1][0], 0, 0, 0);
            acc[1][1] = __builtin_amdgcn_mfma_f32_32x32x16_bf16(ah1, bh1, acc[1][1], 0, 0, 0);
            acc[0][0] = __builtin_amdgcn_mfma_f32_32x32x16_bf16(ah0, bl0, acc[0][0], 0, 0, 0);
            acc[0][1] = __builtin_amdgcn_mfma_f32_32x32x16_bf16(ah0, bl1, acc[0][1], 0, 0, 0);
            acc[1][0] = __builtin_amdgcn_mfma_f32_32x32x16_bf16(ah1, bl0, acc[1][0], 0, 0, 0);
            acc[1][1] = __builtin_amdgcn_mfma_f32_32x32x16_bf16(ah1, bl1, acc[1][1], 0, 0, 0);
            acc[0][0] = __builtin_amdgcn_mfma_f32_32x32x16_bf16(al0, bh0, acc[0][0], 0, 0, 0);
            acc[0][1] = __builtin_amdgcn_mfma_f32_32x32x16_bf16(al0, bh1, acc[0][1], 0, 0, 0);
            acc[1][0] = __builtin_amdgcn_mfma_f32_32x32x16_bf16(al1, bh0, acc[1][0], 0, 0, 0);
            acc[1][1] = __builtin_amdgcn_mfma_f32_32x32x16_bf16(al1, bh1, acc[1][1], 0, 0, 0);
        }
        __syncthreads();
    }

    // C/D layout (32x32, m74/m101): col = lane&31, row = (reg&3)+8*(reg>>2)+4*kh
    if (MODE == 0) {
        #pragma unroll
        for (int i = 0; i < 2; ++i)
            #pragma unroll
            for (int rg = 0; rg < 4; ++rg)
                #pragma unroll
                for (int rr = 0; rr < 4; ++rr) {
                    int reg = rg * 4 + rr;
                    int m = bm + wm * 64 + i * 32 + rr + rg * 8 + kh * 4;
                    #pragma unroll
                    for (int j = 0; j < 2; ++j) {
                        int n = bn + wn * 64 + j * 32 + col;
                        if (n < bRows) C[(size_t)m * ldc + n] = acc[i][j][reg];
                    }
                }
    } else {
        #pragma unroll
        for (int i = 0; i < 2; ++i)
            #pragma unroll
            for (int rg = 0; rg < 4; ++rg)
                #pragma unroll
                for (int rr = 0; rr < 4; ++rr) {
                    int reg = rg * 4 + rr;
                    int m = bm + wm * 64 + i * 32 + rr + rg * 8 + kh * 4;
                    unsigned long long best = 0ull;
                    #pragma unroll
                    for (int j = 0; j < 2; ++j) {
                        int n = bn + wn * 64 + j * 32 + col;
                        if (n < bRows) {
                            float v = acc[i][j][reg] + bias[n];
                            unsigned int u   = __float_as_uint(v);
                            unsigned int key = (u & 0x80000000u) ? ~u : (u | 0x80000000u);
                            unsigned long long pk =
                                ((unsigned long long)key << 32) |
                                (unsigned long long)(0xFFFFFFFFu - (unsigned)n);
                            best = (pk > best) ? pk : best;
                        }
                    }
                    #pragma unroll
                    for (int sdist = 1; sdist < 32; sdist <<= 1) {
                        unsigned long long o = __shfl_xor(best, sdist, 64);
                        best = (o > best) ? o : best;
                    }
                    if (col == 0) atomicMax(&packed[m], best);
                }
    }
}

// gates: NN=16 n-strips; 1-D grid, XCD-affine: r=l&7 -> p=r*PPX+(q>>3)
template<int PPX>
__global__ __launch_bounds__(512, 2) void k_gemm_gates(
    const unsigned short* Ahi, const unsigned short* Alo,
    const unsigned short* Bhi, const unsigned short* Blo,
    float* C, size_t aks, size_t bks, size_t czs) {
    const int l = blockIdx.x, r = l & 7, q = l >> 3;
    const int p = r * PPX + (q >> 3);
    const int mblk = q & 7, nblk = p & 15, kz = p >> 4;
    gemm_pc<0>(Ahi, Alo, 1024, Bhi, Blo, NGATE, C, NGATE, aks, bks, czs,
               mblk * 128, nblk * 128, kz, nullptr, nullptr);
}
// feats: NN=4 n-strips, NZ=8 -> PPX=4
__global__ __launch_bounds__(512, 2) void k_gemm_feats(
    const unsigned short* Ahi, const unsigned short* Alo,
    const unsigned short* Bhi, const unsigned short* Blo,
    float* C) {
    const int l = blockIdx.x, r = l & 7, q = l >> 3;
    const int p = r * 4 + (q >> 3);
    const int mblk = q & 7, nblk = p & 3, kz = p >> 2;
    gemm_pc<0>(Ahi, Alo, 1024, Bhi, Blo, 512, C, 512,
               (size_t)64 * 1024 * 8, (size_t)64 * 512 * 8, (size_t)1024 * 512,
               mblk * 128, nblk * 128, kz, nullptr, nullptr);
}
// logits: NN=94 special XCD-affine map (94 = 8*11 + 6). Bijective.
__global__ __launch_bounds__(512, 2) void k_logits_argmax(
    const unsigned short* __restrict__ h_hi, const unsigned short* __restrict__ h_lo,
    const unsigned short* __restrict__ wout_hi, const unsigned short* __restrict__ wout_lo,
    const float* __restrict__ bias, unsigned long long* __restrict__ packed) {
    int mblk, nblk;
    {
        const int l = blockIdx.x, r = l & 7, q = l >> 3;   // 752 = 8 * 94
        if (q < 88) { nblk = r * 11 + (q >> 3); mblk = q & 7; }
        else        { nblk = 88 + (q - 88);     mblk = r;     }
    }
    gemm_pc<1>(h_hi, h_lo, 1024, wout_hi, wout_lo, NVOCAB, nullptr, 0,
               0, 0, 0, mblk * 128, nblk * 128, 0, bias, packed);
}

// ---------------------------------------------------------------------------
// feats reduce: sum 8 split-K partials + bias, relu, split -> imgv blocked
// ---------------------------------------------------------------------------
__global__ void feats_reduce8(const float* __restrict__ part, const float* __restrict__ bias,
                              unsigned short* __restrict__ hi, unsigned short* __restrict__ lo) {
    int idx = blockIdx.x * 256 + threadIdx.x;   // 1024*64
    int b = idx >> 6, kc = idx & 63;
    int n = kc << 3;
    float v[8];
    #pragma unroll
    for (int e = 0; e < 8; ++e) v[e] = bias[n + e];
    #pragma unroll
    for (int z = 0; z < 8; ++z) {
        const float* s = part + (size_t)z * 1024 * 512 + (size_t)b * 512 + n;
        #pragma unroll
        for (int e = 0; e < 8; ++e) v[e] += s[e];
    }
    us8 vh, vl;
    #pragma unroll
    for (int e = 0; e < 8; ++e) {
        bfpair q = split2v(fmaxf(v[e], 0.f));
        vh[e] = q.hi; vl[e] = q.lo;
    }
    size_t o = ((size_t)kc * 1024 + b) * 8;
    *(us8*)(hi + o) = vh;
    *(us8*)(lo + o) = vl;
}

// ---------------------------------------------------------------------------
// LSTM pointwise; h -> xh slabs kc=64+j8; emits out[b][t-1] then zeroes packed
// ---------------------------------------------------------------------------
template<bool PRIME>
__global__ void lstm_pw_blk(const float* __restrict__ g0, const float* __restrict__ g1,
                            const float* __restrict__ bsum, float* __restrict__ cbuf,
                            unsigned short* __restrict__ xh_hi, unsigned short* __restrict__ xh_lo,
                            unsigned long long* __restrict__ packed,
                            int* __restrict__ out, int t) {
    int idx = blockIdx.x * 256 + threadIdx.x;   // 1024*64
    int b = idx >> 6, j8 = idx & 63;
    int j = j8 << 3;
    const float* g = g0 + (size_t)b * NGATE;
    float v[4][8];
    #pragma unroll
    for (int gt = 0; gt < 4; ++gt) {
        const float* s = g + gt * 512 + j;
        const float* bs = bsum + gt * 512 + j;
        #pragma unroll
        for (int e = 0; e < 8; ++e) v[gt][e] = s[e] + bs[e];
    }
    if (!PRIME) {
        const float* h2 = g1 + (size_t)b * NGATE;
        #pragma unroll
        for (int gt = 0; gt < 4; ++gt) {
            const float* s = h2 + gt * 512 + j;
            #pragma unroll
            for (int e = 0; e < 8; ++e) v[gt][e] += s[e];
        }
    }
    float* cb = cbuf + (size_t)b * 512 + j;
    us8 vh, vl;
    #pragma unroll
    for (int e = 0; e < 8; ++e) {
        float si = 1.f / (1.f + expf(-v[0][e]));
        float sf = 1.f / (1.f + expf(-v[1][e]));
        float tg = tanhf(v[2][e]);
        float so = 1.f / (1.f + expf(-v[3][e]));
        float cn = PRIME ? (si * tg) : (sf * cb[e] + si * tg);
        cb[e] = cn;
        bfpair q = split2v(so * tanhf(cn));
        vh[e] = q.hi; vl[e] = q.lo;
    }
    size_t o = ((size_t)(64 + j8) * 1024 + b) * 8;
    *(us8*)(xh_hi + o) = vh;
    *(us8*)(xh_lo + o) = vl;
    if (j8 == 0) {
        if (!PRIME && t > 0) {
            unsigned long long p = packed[b];
            out[b * SEQLEN + (t - 1)] = (int)(0xFFFFFFFFu - (unsigned)(p & 0xFFFFFFFFull));
        }
        packed[b] = 0ull;
    }
}

// ---------------------------------------------------------------------------
// embedding gather + split into xh slabs kc=0..63 (word from packed / START)
// ---------------------------------------------------------------------------
template<int FIRST>
__global__ void gather_blk(const float* __restrict__ emb,
                           const unsigned long long* __restrict__ packed,
                           unsigned short* __restrict__ xh_hi, unsigned short* __restrict__ xh_lo) {
    int idx = blockIdx.x * 256 + threadIdx.x;   // 1024*64
    int b = idx >> 6, kc = idx & 63;
    int word = 1;
    if (!FIRST) {
        unsigned long long p = packed[b];
        word = (int)(0xFFFFFFFFu - (unsigned)(p & 0xFFFFFFFFull)) + 2;
    }
    us8 vh, vl; split8(emb + (size_t)word * 512 + (kc << 3), vh, vl);
    size_t o = ((size_t)kc * 1024 + b) * 8;
    *(us8*)(xh_hi + o) = vh;
    *(us8*)(xh_lo + o) = vl;
}

__global__ void final_out(const unsigned long long* __restrict__ packed, int* __restrict__ out) {
    int b = blockIdx.x * 256 + threadIdx.x;
    if (b < BATCH) {
        unsigned long long p = packed[b];
        out[b * SEQLEN + (SEQLEN - 1)] = (int)(0xFFFFFFFFu - (unsigned)(p & 0xFFFFFFFFull));
    }
}

extern "C" void kernel_launch(void* const* d_in, const int* in_sizes, int n_in,
                              void* d_out, int out_size, void* d_ws, size_t ws_size,
                              hipStream_t stream) {
    const float* img     = (const float*)d_in[0];
    const float* W_feats = (const float*)d_in[1];
    const float* b_feats = (const float*)d_in[2];
    const float* W_ih    = (const float*)d_in[3];
    const float* W_hh    = (const float*)d_in[4];
    const float* b_ih    = (const float*)d_in[5];
    const float* b_hh    = (const float*)d_in[6];
    const float* emb     = (const float*)d_in[7];
    const float* W_out   = (const float*)d_in[8];
    const float* b_out   = (const float*)d_in[9];
    int* out = (int*)d_out;

    const size_t WCAT_H = (size_t)128 * 2048 * 8;
    const size_t WOUT_H = (size_t)64 * NVOCAB * 8;
    const size_t XH_H   = (size_t)128 * 1024 * 8;
    const size_t IMGV_H = (size_t)64 * 1024 * 8;

    char* p = (char*)d_ws;
    unsigned short* wcat_hi = (unsigned short*)p;  p += WCAT_H * 2;
    unsigned short* wcat_lo = (unsigned short*)p;  p += WCAT_H * 2;
    unsigned short* wout_hi = (unsigned short*)p;  p += WOUT_H * 2;
    unsigned short* wout_lo = (unsigned short*)p;  p += WOUT_H * 2;
    unsigned short* xh_hi   = (unsigned short*)p;  p += XH_H * 2;
    unsigned short* xh_lo   = (unsigned short*)p;  p += XH_H * 2;
    unsigned short* imgv_hi = (unsigned short*)p;  p += IMGV_H * 2;
    unsigned short* imgv_lo = (unsigned short*)p;  p += IMGV_H * 2;
    float* cbuf             = (float*)p;           p += (size_t)1024 * 512 * 4;
    float* bsum             = (float*)p;           p += (size_t)NGATE * 4;
    unsigned long long* packed = (unsigned long long*)p;  p += (size_t)1024 * 8;
    float* gates0           = (float*)p;           p += (size_t)1024 * NGATE * 4;
    float* gates1           = (float*)p;           p += (size_t)1024 * NGATE * 4;
    // transient blocked feats inputs alias the not-yet-written wout region
    unsigned short* imgb_hi = wout_hi;
    unsigned short* imgb_lo = imgb_hi + (size_t)512 * 1024 * 8;
    unsigned short* wfb_hi  = imgb_lo + (size_t)512 * 1024 * 8;
    unsigned short* wfb_lo  = wfb_hi  + (size_t)512 * 512 * 8;
    float* partials = gates0;   // 8 x (1024x512) fp32 = gates0+gates1 region

    // ---- one-time prep
    prep_wcat_blk<<<1024, 256, 0, stream>>>(W_ih, W_hh, b_ih, b_hh, wcat_hi, wcat_lo, bsum);
    prep_blk<<<dim3(4, 512), 256, 0, stream>>>(img,     imgb_hi, imgb_lo, 1024, FEATS);
    prep_blk<<<dim3(2, 512), 256, 0, stream>>>(W_feats, wfb_hi,  wfb_lo,  512,  FEATS);

    // feats: partials[z] = img(chunk z) @ W_feats(chunk z)^T, split-K x8
    k_gemm_feats<<<256, 512, 0, stream>>>(imgb_hi, imgb_lo, wfb_hi, wfb_lo, partials);
    feats_reduce8<<<256, 256, 0, stream>>>(partials, b_feats, imgv_hi, imgv_lo);

    // feats transients dead -> build blocked W_out in place
    prep_blk<<<dim3(47, 64), 256, 0, stream>>>(W_out, wout_hi, wout_lo, NVOCAB, 512);

    // prime LSTM: gates0 = imgv @ W_ih^T (Wcat kc 0..63); NZ=1 -> PPX=2
    k_gemm_gates<2><<<128, 512, 0, stream>>>(imgv_hi, imgv_lo, wcat_hi, wcat_lo,
                                             gates0, 0, 0, 0);
    lstm_pw_blk<true><<<256, 256, 0, stream>>>(gates0, nullptr, bsum, cbuf,
                                               xh_hi, xh_lo, packed, out, 0);

    for (int t = 0; t < SEQLEN; ++t) {
        if (t == 0) gather_blk<1><<<256, 256, 0, stream>>>(emb, packed, xh_hi, xh_lo);
        else        gather_blk<0><<<256, 256, 0, stream>>>(emb, packed, xh_hi, xh_lo);
        // gates{0,1} = xh(kc chunk z) @ Wcat(kc chunk z)^T, split-K x2; PPX=4
        k_gemm_gates<4><<<256, 512, 0, stream>>>(
            xh_hi, xh_lo, wcat_hi, wcat_lo, gates0,
            (size_t)64 * 1024 * 8, (size_t)64 * 2048 * 8, (size_t)1024 * NGATE);
        lstm_pw_blk<false><<<256, 256, 0, stream>>>(gates0, gates1, bsum, cbuf,
                                                    xh_hi, xh_lo, packed, out, t);
        // logits = h @ W_out^T + b_out, fused argmax (A = h slabs kc 64..127)
        k_logits_argmax<<<752, 512, 0, stream>>>(
            xh_hi + (size_t)64 * 1024 * 8, xh_lo + (size_t)64 * 1024 * 8,
            wout_hi, wout_lo, b_out, packed);
    }
    final_out<<<4, 256, 0, stream>>>(packed, out);
}

// Round 11
// 1618.429 us; speedup vs baseline: 3.1983x; 3.1983x over previous
//
#include <hip/hip_runtime.h>
#include <stdint.h>

#define BATCH  1024
#define SEQLEN 15
#define NGATE  2048
#define NVOCAB 11998
#define FEATS  4096

typedef __attribute__((ext_vector_type(8)))  short  s8v;     // 8 bf16 bit patterns
typedef __attribute__((ext_vector_type(16))) float  f32x16;  // 32x32 MFMA acc
typedef __attribute__((ext_vector_type(8)))  unsigned short us8;

__device__ __forceinline__ unsigned short f2bf(float f) {
    unsigned u = __float_as_uint(f);
    u += 0x7FFFu + ((u >> 16) & 1u);
    return (unsigned short)(u >> 16);
}
__device__ __forceinline__ float bf2f(unsigned short h) {
    return __uint_as_float(((unsigned)h) << 16);
}
struct bfpair { unsigned short hi, lo; };
__device__ __forceinline__ bfpair split2v(float v) {
    bfpair r;
    r.hi = f2bf(v);
    r.lo = f2bf(v - bf2f(r.hi));
    return r;
}
__device__ __forceinline__ void split8(const float* __restrict__ s, us8& vh, us8& vl) {
    #pragma unroll
    for (int e = 0; e < 8; ++e) {
        bfpair q = split2v(s[e]);
        vh[e] = q.hi; vl[e] = q.lo;
    }
}

// async 16B-per-lane global->LDS; LDS dest = wave-uniform base + lane*16
__device__ __forceinline__ void async_cp16(const void* g, void* l) {
    __builtin_amdgcn_global_load_lds(
        (const __attribute__((address_space(1))) unsigned int*)g,
        (__attribute__((address_space(3))) unsigned int*)l, 16, 0, 0);
}

// ---------------------------------------------------------------------------
// prep: Wcat blocked [128 kc][2048 row][8] = split([W_ih | W_hh]); bsum
// ---------------------------------------------------------------------------
__global__ void prep_wcat_blk(const float* __restrict__ W_ih, const float* __restrict__ W_hh,
                              const float* __restrict__ b_ih, const float* __restrict__ b_hh,
                              unsigned short* __restrict__ hi, unsigned short* __restrict__ lo,
                              float* __restrict__ bsum) {
    int idx = blockIdx.x * 256 + threadIdx.x;   // 128*2048
    int kc = idx >> 11, row = idx & 2047;
    int k = kc << 3;
    const float* src = (k < 512) ? (W_ih + (size_t)row * 512 + k)
                                 : (W_hh + (size_t)row * 512 + (k - 512));
    us8 vh, vl; split8(src, vh, vl);
    *(us8*)(hi + (size_t)idx * 8) = vh;
    *(us8*)(lo + (size_t)idx * 8) = vl;
    if (idx < NGATE) bsum[idx] = b_ih[idx] + b_hh[idx];
}

// src [R][K] fp32 -> hi/lo [K/8][R][8] bf16. grid: (ceil(R/256), K/8)
__global__ void prep_blk(const float* __restrict__ src,
                         unsigned short* __restrict__ hi, unsigned short* __restrict__ lo,
                         int R, int K) {
    int row = blockIdx.x * 256 + threadIdx.x;
    if (row >= R) return;
    int kc = blockIdx.y;
    us8 vh, vl; split8(src + (size_t)row * K + (kc << 3), vh, vl);
    size_t o = ((size_t)kc * R + row) * 8;
    *(us8*)(hi + o) = vh;
    *(us8*)(lo + o) = vl;
}

// ---------------------------------------------------------------------------
// Round-0 proven GEMM body for gates/feats (single-buffered global_load_lds
// staging, K8-blocked operands [kc][rows][8], 128x128 tile, 4 waves 2x2 of
// 64x64, 32x32x16 bf16 MFMA, 3-product split). (bm, bn, kz) from wrappers
// (XCD-affine swizzle). This exact body+swizzle measured best for gates (R5).
// ---------------------------------------------------------------------------
__device__ __forceinline__ void mfma_blk_store(
    const unsigned short* __restrict__ Ahi, const unsigned short* __restrict__ Alo, int aRows,
    const unsigned short* __restrict__ Bhi, const unsigned short* __restrict__ Blo, int bRows,
    float* __restrict__ C, int ldc,
    int K, size_t akstride, size_t bkstride, size_t czstride,
    int bm, int bn, int kz)
{
    __shared__ short smem[4 * 4 * 128 * 8];   // 32 KB
    short* sAhi = smem;
    short* sAlo = smem + 4 * 128 * 8;
    short* sBhi = smem + 2 * 4 * 128 * 8;
    short* sBlo = smem + 3 * 4 * 128 * 8;

    Ahi += (size_t)kz * akstride;  Alo += (size_t)kz * akstride;
    Bhi += (size_t)kz * bkstride;  Blo += (size_t)kz * bkstride;
    C   += (size_t)kz * czstride;

    const int tid  = threadIdx.x;
    const int lane = tid & 63, wave = tid >> 6;
    const int wr = (wave & 1) * 64, wc = (wave >> 1) * 64;
    const int col = lane & 31, kh = lane >> 5;

    f32x16 acc[2][2] = {};

    for (int k0 = 0; k0 < K; k0 += 32) {
        const int kc0 = k0 >> 3;
        __syncthreads();
        #pragma unroll
        for (int p = 0; p < 2; ++p) {
            int s    = p * 4 + wave;
            int kc_l = s >> 1, rh = s & 1;
            int rl   = rh * 64 + lane;
            int lo_  = (kc_l * 128 + rh * 64) * 8;
            size_t ga = ((size_t)(kc0 + kc_l) * aRows + (bm + rl)) * 8;
            async_cp16(Ahi + ga, sAhi + lo_);
            async_cp16(Alo + ga, sAlo + lo_);
            int brow = bn + rl; if (brow > bRows - 1) brow = bRows - 1;
            size_t gb = ((size_t)(kc0 + kc_l) * bRows + brow) * 8;
            async_cp16(Bhi + gb, sBhi + lo_);
            async_cp16(Blo + gb, sBlo + lo_);
        }
        __syncthreads();

        #pragma unroll
        for (int st = 0; st < 2; ++st) {
            int off = (2 * st + kh) * 128 * 8;
            s8v ah0 = *(const s8v*)(sAhi + off + (wr + col) * 8);
            s8v ah1 = *(const s8v*)(sAhi + off + (wr + 32 + col) * 8);
            s8v al0 = *(const s8v*)(sAlo + off + (wr + col) * 8);
            s8v al1 = *(const s8v*)(sAlo + off + (wr + 32 + col) * 8);
            s8v bh0 = *(const s8v*)(sBhi + off + (wc + col) * 8);
            s8v bh1 = *(const s8v*)(sBhi + off + (wc + 32 + col) * 8);
            s8v bl0 = *(const s8v*)(sBlo + off + (wc + col) * 8);
            s8v bl1 = *(const s8v*)(sBlo + off + (wc + 32 + col) * 8);
            acc[0][0] = __builtin_amdgcn_mfma_f32_32x32x16_bf16(ah0, bh0, acc[0][0], 0, 0, 0);
            acc[0][1] = __builtin_amdgcn_mfma_f32_32x32x16_bf16(ah0, bh1, acc[0][1], 0, 0, 0);
            acc[1][0] = __builtin_amdgcn_mfma_f32_32x32x16_bf16(ah1, bh0, acc[1][0], 0, 0, 0);
            acc[1][1] = __builtin_amdgcn_mfma_f32_32x32x16_bf16(ah1, bh1, acc[1][1], 0, 0, 0);
            acc[0][0] = __builtin_amdgcn_mfma_f32_32x32x16_bf16(ah0, bl0, acc[0][0], 0, 0, 0);
            acc[0][1] = __builtin_amdgcn_mfma_f32_32x32x16_bf16(ah0, bl1, acc[0][1], 0, 0, 0);
            acc[1][0] = __builtin_amdgcn_mfma_f32_32x32x16_bf16(ah1, bl0, acc[1][0], 0, 0, 0);
            acc[1][1] = __builtin_amdgcn_mfma_f32_32x32x16_bf16(ah1, bl1, acc[1][1], 0, 0, 0);
            acc[0][0] = __builtin_amdgcn_mfma_f32_32x32x16_bf16(al0, bh0, acc[0][0], 0, 0, 0);
            acc[0][1] = __builtin_amdgcn_mfma_f32_32x32x16_bf16(al0, bh1, acc[0][1], 0, 0, 0);
            acc[1][0] = __builtin_amdgcn_mfma_f32_32x32x16_bf16(al1, bh0, acc[1][0], 0, 0, 0);
            acc[1][1] = __builtin_amdgcn_mfma_f32_32x32x16_bf16(al1, bh1, acc[1][1], 0, 0, 0);
        }
    }

    // C/D layout (32x32, m74/m101): col = lane&31, row = (reg&3)+8*(reg>>2)+4*kh
    #pragma unroll
    for (int i = 0; i < 2; ++i)
        #pragma unroll
        for (int rg = 0; rg < 4; ++rg)
            #pragma unroll
            for (int rr = 0; rr < 4; ++rr) {
                int reg = rg * 4 + rr;
                int m = bm + wr + i * 32 + rr + rg * 8 + kh * 4;
                #pragma unroll
                for (int j = 0; j < 2; ++j) {
                    int n = bn + wc + j * 32 + col;
                    if (n < bRows) C[(size_t)m * ldc + n] = acc[i][j][reg];
                }
            }
}

// gates: NN=16 n-strips; 1-D grid, XCD-affine: r=l&7 -> p=r*PPX+(q>>3)
template<int PPX>
__global__ __launch_bounds__(256) void k_gemm_gates(
    const unsigned short* Ahi, const unsigned short* Alo,
    const unsigned short* Bhi, const unsigned short* Blo,
    float* C, size_t aks, size_t bks, size_t czs) {
    const int l = blockIdx.x, r = l & 7, q = l >> 3;
    const int p = r * PPX + (q >> 3);
    const int mblk = q & 7, nblk = p & 15, kz = p >> 4;
    mfma_blk_store(Ahi, Alo, 1024, Bhi, Blo, NGATE, C, NGATE, 512, aks, bks, czs,
                   mblk * 128, nblk * 128, kz);
}
// feats: NN=4 n-strips, NZ=8 -> PPX=4
__global__ __launch_bounds__(256) void k_gemm_feats(
    const unsigned short* Ahi, const unsigned short* Alo,
    const unsigned short* Bhi, const unsigned short* Blo,
    float* C) {
    const int l = blockIdx.x, r = l & 7, q = l >> 3;
    const int p = r * 4 + (q >> 3);
    const int mblk = q & 7, nblk = p & 3, kz = p >> 2;
    mfma_blk_store(Ahi, Alo, 1024, Bhi, Blo, 512, C, 512, 512,
                   (size_t)64 * 1024 * 8, (size_t)64 * 512 * 8, (size_t)1024 * 512,
                   mblk * 128, nblk * 128, kz);
}

// ---------------------------------------------------------------------------
// logits v10 = R3's proven 74 µs body (4 waves 2x2, 128x128, A direct
// global->reg, B double-buffered LDS via global_load_lds, stage-before-
// compute, one drain barrier per 32-K step) + A-REGISTER PREFETCH: A(t+1)
// issued alongside B-stage(t+1) BEFORE compute(t), so after the barrier the
// next step's MFMAs start with zero exposed A-latency. Only delta vs R3.
// Per-accumulator FP chain unchanged (hh, hl, lh per ascending k-slice) ->
// bit-identical tokens. Fused bias + packed-argmax epilogue.
// XCD-affine map: 94 = 8*11 + 6 (88 strips pinned, 6 spread). Bijective.
// ---------------------------------------------------------------------------
__global__ __launch_bounds__(256, 3) void k_logits_argmax(
    const unsigned short* __restrict__ h_hi, const unsigned short* __restrict__ h_lo,
    const unsigned short* __restrict__ wout_hi, const unsigned short* __restrict__ wout_lo,
    const float* __restrict__ bias, unsigned long long* __restrict__ packed)
{
    __shared__ short sB[2][2][4][128][8];   // buf, hi/lo, kc_l, row, 8 = 32 KB

    int mblk, nblk;
    {
        const int l = blockIdx.x, r = l & 7, q = l >> 3;   // 752 = 8 * 94
        if (q < 88) { nblk = r * 11 + (q >> 3); mblk = q & 7; }
        else        { nblk = 88 + (q - 88);     mblk = r;     }
    }

    const int tid  = threadIdx.x;
    const int lane = tid & 63, wave = tid >> 6;
    const int wm = wave & 1, wn = wave >> 1;
    const int col = lane & 31, kh = lane >> 5;
    const int bm = mblk * 128, bn = nblk * 128;
    const int aRows = 1024, bRows = NVOCAB;

    f32x16 acc[2][2] = {};

    // stage one 16 KB B K-tile (4 kc) into sB[bufi]: 16 slabs, 4 per wave
    auto stage_B = [&](int kcbase, int bufi) {
        #pragma unroll
        for (int p = 0; p < 4; ++p) {
            int s = p * 4 + wave;
            int arr = s >> 3, kc_l = (s >> 1) & 3, rh = s & 1;
            int brow = bn + rh * 64 + lane; if (brow > bRows - 1) brow = bRows - 1;
            size_t gb = ((size_t)(kcbase + kc_l) * bRows + brow) * 8;
            async_cp16((arr ? wout_lo : wout_hi) + gb, &sB[bufi][arr][kc_l][rh * 64][0]);
        }
    };
    // load A frags for one 32-K tile direct to regs (8 x dwordx4)
    auto load_A = [&](int kc0, s8v (&ah)[2][2], s8v (&al)[2][2]) {
        #pragma unroll
        for (int st = 0; st < 2; ++st)
            #pragma unroll
            for (int i = 0; i < 2; ++i) {
                size_t ao = ((size_t)(kc0 + 2 * st + kh) * aRows
                             + (bm + wm * 64 + i * 32 + col)) * 8;
                ah[st][i] = *(const s8v*)(h_hi + ao);
                al[st][i] = *(const s8v*)(h_lo + ao);
            }
    };

    // prologue: B(0) staged, A(0) loaded; drain once
    stage_B(0, 0);
    s8v ahc[2][2], alc[2][2], ahn[2][2], aln[2][2];
    load_A(0, ahc, alc);
    __syncthreads();

    int cur = 0;
    for (int ks = 0; ks < 16; ++ks) {
        // issue next tile's B-stage AND A-loads before compute: the drain at
        // this step's barrier covers both under the MFMA phase
        if (ks + 1 < 16) {
            stage_B((ks + 1) << 2, cur ^ 1);
            load_A((ks + 1) << 2, ahn, aln);
        }

        #pragma unroll
        for (int st = 0; st < 2; ++st) {
            const int kl = 2 * st + kh;
            #pragma unroll
            for (int j = 0; j < 2; ++j) {
                const s8v bh = *(const s8v*)&sB[cur][0][kl][wn * 64 + j * 32 + col][0];
                const s8v bl = *(const s8v*)&sB[cur][1][kl][wn * 64 + j * 32 + col][0];
                #pragma unroll
                for (int i = 0; i < 2; ++i) {
                    acc[i][j] = __builtin_amdgcn_mfma_f32_32x32x16_bf16(ahc[st][i], bh, acc[i][j], 0, 0, 0);
                    acc[i][j] = __builtin_amdgcn_mfma_f32_32x32x16_bf16(ahc[st][i], bl, acc[i][j], 0, 0, 0);
                    acc[i][j] = __builtin_amdgcn_mfma_f32_32x32x16_bf16(alc[st][i], bh, acc[i][j], 0, 0, 0);
                }
            }
        }

        __syncthreads();   // drains vmcnt(0): B(t+1) resident, A(t+1) in regs
        cur ^= 1;
        if (ks + 1 < 16) {
            #pragma unroll
            for (int st = 0; st < 2; ++st)
                #pragma unroll
                for (int i = 0; i < 2; ++i) {
                    ahc[st][i] = ahn[st][i];
                    alc[st][i] = aln[st][i];
                }
        }
    }

    // argmax epilogue: col = lane&31, row = (reg&3)+8*(reg>>2)+4*kh
    #pragma unroll
    for (int i = 0; i < 2; ++i)
        #pragma unroll
        for (int rg = 0; rg < 4; ++rg)
            #pragma unroll
            for (int rr = 0; rr < 4; ++rr) {
                int reg = rg * 4 + rr;
                int m = bm + wm * 64 + i * 32 + rr + rg * 8 + kh * 4;
                unsigned long long best = 0ull;
                #pragma unroll
                for (int j = 0; j < 2; ++j) {
                    int n = bn + wn * 64 + j * 32 + col;
                    if (n < bRows) {
                        float v = acc[i][j][reg] + bias[n];
                        unsigned int u   = __float_as_uint(v);
                        unsigned int key = (u & 0x80000000u) ? ~u : (u | 0x80000000u);
                        unsigned long long pk =
                            ((unsigned long long)key << 32) |
                            (unsigned long long)(0xFFFFFFFFu - (unsigned)n);
                        best = (pk > best) ? pk : best;
                    }
                }
                #pragma unroll
                for (int sdist = 1; sdist < 32; sdist <<= 1) {
                    unsigned long long o = __shfl_xor(best, sdist, 64);
                    best = (o > best) ? o : best;
                }
                if (col == 0) atomicMax(&packed[m], best);
            }
}

// ---------------------------------------------------------------------------
// feats reduce: sum 8 split-K partials + bias, relu, split -> imgv blocked
// ---------------------------------------------------------------------------
__global__ void feats_reduce8(const float* __restrict__ part, const float* __restrict__ bias,
                              unsigned short* __restrict__ hi, unsigned short* __restrict__ lo) {
    int idx = blockIdx.x * 256 + threadIdx.x;   // 1024*64
    int b = idx >> 6, kc = idx & 63;
    int n = kc << 3;
    float v[8];
    #pragma unroll
    for (int e = 0; e < 8; ++e) v[e] = bias[n + e];
    #pragma unroll
    for (int z = 0; z < 8; ++z) {
        const float* s = part + (size_t)z * 1024 * 512 + (size_t)b * 512 + n;
        #pragma unroll
        for (int e = 0; e < 8; ++e) v[e] += s[e];
    }
    us8 vh, vl;
    #pragma unroll
    for (int e = 0; e < 8; ++e) {
        bfpair q = split2v(fmaxf(v[e], 0.f));
        vh[e] = q.hi; vl[e] = q.lo;
    }
    size_t o = ((size_t)kc * 1024 + b) * 8;
    *(us8*)(hi + o) = vh;
    *(us8*)(lo + o) = vl;
}

// ---------------------------------------------------------------------------
// LSTM pointwise; h -> xh slabs kc=64+j8; emits out[b][t-1] then zeroes packed
// ---------------------------------------------------------------------------
template<bool PRIME>
__global__ void lstm_pw_blk(const float* __restrict__ g0, const float* __restrict__ g1,
                            const float* __restrict__ bsum, float* __restrict__ cbuf,
                            unsigned short* __restrict__ xh_hi, unsigned short* __restrict__ xh_lo,
                            unsigned long long* __restrict__ packed,
                            int* __restrict__ out, int t) {
    int idx = blockIdx.x * 256 + threadIdx.x;   // 1024*64
    int b = idx >> 6, j8 = idx & 63;
    int j = j8 << 3;
    const float* g = g0 + (size_t)b * NGATE;
    float v[4][8];
    #pragma unroll
    for (int gt = 0; gt < 4; ++gt) {
        const float* s = g + gt * 512 + j;
        const float* bs = bsum + gt * 512 + j;
        #pragma unroll
        for (int e = 0; e < 8; ++e) v[gt][e] = s[e] + bs[e];
    }
    if (!PRIME) {
        const float* h2 = g1 + (size_t)b * NGATE;
        #pragma unroll
        for (int gt = 0; gt < 4; ++gt) {
            const float* s = h2 + gt * 512 + j;
            #pragma unroll
            for (int e = 0; e < 8; ++e) v[gt][e] += s[e];
        }
    }
    float* cb = cbuf + (size_t)b * 512 + j;
    us8 vh, vl;
    #pragma unroll
    for (int e = 0; e < 8; ++e) {
        float si = 1.f / (1.f + expf(-v[0][e]));
        float sf = 1.f / (1.f + expf(-v[1][e]));
        float tg = tanhf(v[2][e]);
        float so = 1.f / (1.f + expf(-v[3][e]));
        float cn = PRIME ? (si * tg) : (sf * cb[e] + si * tg);
        cb[e] = cn;
        bfpair q = split2v(so * tanhf(cn));
        vh[e] = q.hi; vl[e] = q.lo;
    }
    size_t o = ((size_t)(64 + j8) * 1024 + b) * 8;
    *(us8*)(xh_hi + o) = vh;
    *(us8*)(xh_lo + o) = vl;
    if (j8 == 0) {
        if (!PRIME && t > 0) {
            unsigned long long p = packed[b];
            out[b * SEQLEN + (t - 1)] = (int)(0xFFFFFFFFu - (unsigned)(p & 0xFFFFFFFFull));
        }
        packed[b] = 0ull;
    }
}

// ---------------------------------------------------------------------------
// embedding gather + split into xh slabs kc=0..63 (word from packed / START)
// ---------------------------------------------------------------------------
template<int FIRST>
__global__ void gather_blk(const float* __restrict__ emb,
                           const unsigned long long* __restrict__ packed,
                           unsigned short* __restrict__ xh_hi, unsigned short* __restrict__ xh_lo) {
    int idx = blockIdx.x * 256 + threadIdx.x;   // 1024*64
    int b = idx >> 6, kc = idx & 63;
    int word = 1;
    if (!FIRST) {
        unsigned long long p = packed[b];
        word = (int)(0xFFFFFFFFu - (unsigned)(p & 0xFFFFFFFFull)) + 2;
    }
    us8 vh, vl; split8(emb + (size_t)word * 512 + (kc << 3), vh, vl);
    size_t o = ((size_t)kc * 1024 + b) * 8;
    *(us8*)(xh_hi + o) = vh;
    *(us8*)(xh_lo + o) = vl;
}

__global__ void final_out(const unsigned long long* __restrict__ packed, int* __restrict__ out) {
    int b = blockIdx.x * 256 + threadIdx.x;
    if (b < BATCH) {
        unsigned long long p = packed[b];
        out[b * SEQLEN + (SEQLEN - 1)] = (int)(0xFFFFFFFFu - (unsigned)(p & 0xFFFFFFFFull));
    }
}

extern "C" void kernel_launch(void* const* d_in, const int* in_sizes, int n_in,
                              void* d_out, int out_size, void* d_ws, size_t ws_size,
                              hipStream_t stream) {
    const float* img     = (const float*)d_in[0];
    const float* W_feats = (const float*)d_in[1];
    const float* b_feats = (const float*)d_in[2];
    const float* W_ih    = (const float*)d_in[3];
    const float* W_hh    = (const float*)d_in[4];
    const float* b_ih    = (const float*)d_in[5];
    const float* b_hh    = (const float*)d_in[6];
    const float* emb     = (const float*)d_in[7];
    const float* W_out   = (const float*)d_in[8];
    const float* b_out   = (const float*)d_in[9];
    int* out = (int*)d_out;

    const size_t WCAT_H = (size_t)128 * 2048 * 8;
    const size_t WOUT_H = (size_t)64 * NVOCAB * 8;
    const size_t XH_H   = (size_t)128 * 1024 * 8;
    const size_t IMGV_H = (size_t)64 * 1024 * 8;

    char* p = (char*)d_ws;
    unsigned short* wcat_hi = (unsigned short*)p;  p += WCAT_H * 2;
    unsigned short* wcat_lo = (unsigned short*)p;  p += WCAT_H * 2;
    unsigned short* wout_hi = (unsigned short*)p;  p += WOUT_H * 2;
    unsigned short* wout_lo = (unsigned short*)p;  p += WOUT_H * 2;
    unsigned short* xh_hi   = (unsigned short*)p;  p += XH_H * 2;
    unsigned short* xh_lo   = (unsigned short*)p;  p += XH_H * 2;
    unsigned short* imgv_hi = (unsigned short*)p;  p += IMGV_H * 2;
    unsigned short* imgv_lo = (unsigned short*)p;  p += IMGV_H * 2;
    float* cbuf             = (float*)p;           p += (size_t)1024 * 512 * 4;
    float* bsum             = (float*)p;           p += (size_t)NGATE * 4;
    unsigned long long* packed = (unsigned long long*)p;  p += (size_t)1024 * 8;
    float* gates0           = (float*)p;           p += (size_t)1024 * NGATE * 4;
    float* gates1           = (float*)p;           p += (size_t)1024 * NGATE * 4;
    // transient blocked feats inputs alias the not-yet-written wout region
    unsigned short* imgb_hi = wout_hi;
    unsigned short* imgb_lo = imgb_hi + (size_t)512 * 1024 * 8;
    unsigned short* wfb_hi  = imgb_lo + (size_t)512 * 1024 * 8;
    unsigned short* wfb_lo  = wfb_hi  + (size_t)512 * 512 * 8;
    float* partials = gates0;   // 8 x (1024x512) fp32 = gates0+gates1 region

    // ---- one-time prep
    prep_wcat_blk<<<1024, 256, 0, stream>>>(W_ih, W_hh, b_ih, b_hh, wcat_hi, wcat_lo, bsum);
    prep_blk<<<dim3(4, 512), 256, 0, stream>>>(img,     imgb_hi, imgb_lo, 1024, FEATS);
    prep_blk<<<dim3(2, 512), 256, 0, stream>>>(W_feats, wfb_hi,  wfb_lo,  512,  FEATS);

    // feats: partials[z] = img(chunk z) @ W_feats(chunk z)^T, split-K x8
    k_gemm_feats<<<256, 256, 0, stream>>>(imgb_hi, imgb_lo, wfb_hi, wfb_lo, partials);
    feats_reduce8<<<256, 256, 0, stream>>>(partials, b_feats, imgv_hi, imgv_lo);

    // feats transients dead -> build blocked W_out in place
    prep_blk<<<dim3(47, 64), 256, 0, stream>>>(W_out, wout_hi, wout_lo, NVOCAB, 512);

    // prime LSTM: gates0 = imgv @ W_ih^T (Wcat kc 0..63); NZ=1 -> PPX=2
    k_gemm_gates<2><<<128, 256, 0, stream>>>(imgv_hi, imgv_lo, wcat_hi, wcat_lo,
                                             gates0, 0, 0, 0);
    lstm_pw_blk<true><<<256, 256, 0, stream>>>(gates0, nullptr, bsum, cbuf,
                                               xh_hi, xh_lo, packed, out, 0);

    for (int t = 0; t < SEQLEN; ++t) {
        if (t == 0) gather_blk<1><<<256, 256, 0, stream>>>(emb, packed, xh_hi, xh_lo);
        else        gather_blk<0><<<256, 256, 0, stream>>>(emb, packed, xh_hi, xh_lo);
        // gates{0,1} = xh(kc chunk z) @ Wcat(kc chunk z)^T, split-K x2; PPX=4
        k_gemm_gates<4><<<256, 256, 0, stream>>>(
            xh_hi, xh_lo, wcat_hi, wcat_lo, gates0,
            (size_t)64 * 1024 * 8, (size_t)64 * 2048 * 8, (size_t)1024 * NGATE);
        lstm_pw_blk<false><<<256, 256, 0, stream>>>(gates0, gates1, bsum, cbuf,
                                                    xh_hi, xh_lo, packed, out, t);
        // logits = h @ W_out^T + b_out, fused argmax (A = h slabs kc 64..127)
        k_logits_argmax<<<752, 256, 0, stream>>>(
            xh_hi + (size_t)64 * 1024 * 8, xh_lo + (size_t)64 * 1024 * 8,
            wout_hi, wout_lo, b_out, packed);
    }
    final_out<<<4, 256, 0, stream>>>(packed, out);
}